// Round 5
// baseline (253.075 us; speedup 1.0000x reference)
//
#include <hip/hip_runtime.h>

// B=64, N=2048, DIM_IN=DIM_OUT=64, CHEB_K=3, EMBED_DIM=10
#define NN 2048
#define BB 64
#define CC 64
#define ED 10
#define KK 3
#define JJ (BB * CC)   // 4096
#define WROW (KK * CC * CC)  // 12288 elems per Wall node-row

typedef unsigned short ushort_t;
typedef __attribute__((ext_vector_type(8))) short short8;   // 8 bf16 = 4 VGPRs
typedef __attribute__((ext_vector_type(4))) float f32x4;

typedef const __attribute__((address_space(1))) unsigned* gptr_t;
typedef __attribute__((address_space(3))) unsigned* lptr_t;

static __device__ __forceinline__ ushort_t f2bf(float f) {
    union { float f; unsigned u; } x{f};
    unsigned r = x.u + 0x7FFF + ((x.u >> 16) & 1);  // RTN-even
    return (ushort_t)(r >> 16);
}
static __device__ __forceinline__ float bf2f(ushort_t h) {
    union { unsigned u; float f; } x;
    x.u = ((unsigned)h) << 16;
    return x.f;
}

// ---------------------------------------------------------------------------
// Kernel 1: A_bf16[n][m] = softmax(relu(E E^T), axis=1). One block per row n.
// ---------------------------------------------------------------------------
__global__ __launch_bounds__(256) void supports_kernel(const float* __restrict__ E,
                                                       ushort_t* __restrict__ Ab) {
    const int n = blockIdx.x;
    const int tid = threadIdx.x;

    float en[ED];
#pragma unroll
    for (int d = 0; d < ED; ++d) en[d] = E[n * ED + d];

    float sv[NN / 256];
    float lmax = 0.0f;  // relu >= 0
#pragma unroll
    for (int j = 0; j < NN / 256; ++j) {
        const int m = tid + j * 256;
        const float* Em = E + m * ED;
        float dot = 0.0f;
#pragma unroll
        for (int d = 0; d < ED; ++d) dot += en[d] * Em[d];
        float s = fmaxf(dot, 0.0f);
        sv[j] = s;
        lmax = fmaxf(lmax, s);
    }

    __shared__ float smax[4];
    __shared__ float ssum[4];
#pragma unroll
    for (int off = 32; off > 0; off >>= 1) lmax = fmaxf(lmax, __shfl_down(lmax, off, 64));
    if ((tid & 63) == 0) smax[tid >> 6] = lmax;
    __syncthreads();
    const float bmax = fmaxf(fmaxf(smax[0], smax[1]), fmaxf(smax[2], smax[3]));

    float lsum = 0.0f;
#pragma unroll
    for (int j = 0; j < NN / 256; ++j) {
        sv[j] = __expf(sv[j] - bmax);
        lsum += sv[j];
    }
#pragma unroll
    for (int off = 32; off > 0; off >>= 1) lsum += __shfl_down(lsum, off, 64);
    if ((tid & 63) == 0) ssum[tid >> 6] = lsum;
    __syncthreads();
    const float inv = 1.0f / (ssum[0] + ssum[1] + ssum[2] + ssum[3]);

#pragma unroll
    for (int j = 0; j < NN / 256; ++j) {
        Ab[(size_t)n * NN + tid + j * 256] = f2bf(sv[j] * inv);
    }
}

// ---------------------------------------------------------------------------
// Kernel 2: x[b][n][c] fp32 -> xT[(b*64+c)][n] bf16 (K-major for GEMM1 B-op)
//                           and xN[n][(b*64+c)] bf16 (node-major for epilogue).
// ---------------------------------------------------------------------------
__global__ __launch_bounds__(256) void transpose_kernel(const float* __restrict__ x,
                                                        ushort_t* __restrict__ xT,
                                                        ushort_t* __restrict__ xN) {
    const int n0 = blockIdx.x * 64;
    const int b = blockIdx.y;
    const int tid = threadIdx.x;

    __shared__ float tb[64][68];  // tb[c][nn]

#pragma unroll
    for (int l = 0; l < 4; ++l) {
        const int idx = tid + l * 256;
        const int nn = idx >> 4;
        const int c4 = (idx & 15) << 2;
        const float4 v = *(const float4*)(x + ((size_t)b * NN + n0 + nn) * CC + c4);
        tb[c4 + 0][nn] = v.x;
        tb[c4 + 1][nn] = v.y;
        tb[c4 + 2][nn] = v.z;
        tb[c4 + 3][nn] = v.w;
    }
    __syncthreads();

#pragma unroll
    for (int l = 0; l < 2; ++l) {
        const int idx = tid + l * 256;
        const int c = idx >> 3;
        const int ch = (idx & 7) << 3;
        ushort_t pack[8];
#pragma unroll
        for (int e = 0; e < 8; ++e) pack[e] = f2bf(tb[c][ch + e]);
        *(float4*)(xT + (size_t)(b * 64 + c) * NN + n0 + ch) = *(float4*)pack;
    }
#pragma unroll
    for (int l = 0; l < 2; ++l) {
        const int idx = tid + l * 256;
        const int nn = idx >> 3;
        const int cg = (idx & 7) << 3;
        ushort_t pack[8];
#pragma unroll
        for (int e = 0; e < 8; ++e) pack[e] = f2bf(tb[cg + e][nn]);
        *(float4*)(xN + (size_t)(n0 + nn) * JJ + b * 64 + cg) = *(float4*)pack;
    }
}

// ---------------------------------------------------------------------------
// Kernel 2b: Wp[d][k][i][o] fp32 -> WpT[(d*3+k)][o][i] bf16. 30 blocks.
// ---------------------------------------------------------------------------
__global__ __launch_bounds__(256) void wprep_kernel(const float* __restrict__ Wp,
                                                    ushort_t* __restrict__ WpT) {
    const int dk = blockIdx.x;
    const int tid = threadIdx.x;
    const float* src = Wp + (size_t)dk * CC * CC;

    __shared__ float tb[64][68];  // tb[o][i]

#pragma unroll
    for (int l = 0; l < 4; ++l) {
        const int idx = tid + l * 256;
        const int i = idx >> 4;
        const int o4 = (idx & 15) << 2;
        const float4 v = *(const float4*)(src + i * CC + o4);
        tb[o4 + 0][i] = v.x;
        tb[o4 + 1][i] = v.y;
        tb[o4 + 2][i] = v.z;
        tb[o4 + 3][i] = v.w;
    }
    __syncthreads();

#pragma unroll
    for (int l = 0; l < 2; ++l) {
        const int idx = tid + l * 256;
        const int o = idx >> 3;
        const int ic = (idx & 7) << 3;
        ushort_t pack[8];
#pragma unroll
        for (int e = 0; e < 8; ++e) pack[e] = f2bf(tb[o][ic + e]);
        *(float4*)(WpT + (size_t)dk * CC * CC + o * CC + ic) = *(float4*)pack;
    }
}

// ---------------------------------------------------------------------------
// Kernel 2c: Wall[n][k][o][i] bf16 = sum_d E[n,d] * WpT[(d,k)][o][i].
// 4 nodes/block; d-slices cached in registers and reused across nodes.
// Node-row layout: chunk t in [0,1536), t = k*512 + o*8 + ic  (8 i-elems/chunk).
// ---------------------------------------------------------------------------
#define WNPB 4
__global__ __launch_bounds__(256) void wall_kernel(const float* __restrict__ E,
                                                   const ushort_t* __restrict__ WpT,
                                                   ushort_t* __restrict__ Wall,
                                                   int n_base) {
    const int n0 = n_base + blockIdx.x * WNPB;
    const int tid = threadIdx.x;

    __shared__ float es[WNPB][ED];
    if (tid < WNPB * ED) es[tid / ED][tid % ED] = E[(size_t)(n0 + tid / ED) * ED + tid % ED];
    __syncthreads();

#pragma unroll
    for (int c = 0; c < 6; ++c) {
        const int t = c * 256 + tid;       // chunk id in [0,1536)
        const int k = t >> 9;
        const int off = (t & 511) << 3;    // elem offset in the [o][i] matrix
        float vals[ED][8];
#pragma unroll
        for (int d = 0; d < ED; ++d) {
            const float4 p = *(const float4*)(WpT + (size_t)(d * KK + k) * CC * CC + off);
            const ushort_t* pp = (const ushort_t*)&p;
#pragma unroll
            for (int e = 0; e < 8; ++e) vals[d][e] = bf2f(pp[e]);
        }
#pragma unroll
        for (int nl = 0; nl < WNPB; ++nl) {
            float acc[8];
#pragma unroll
            for (int e = 0; e < 8; ++e) acc[e] = 0.0f;
#pragma unroll
            for (int d = 0; d < ED; ++d) {
                const float ed = es[nl][d];
#pragma unroll
                for (int e = 0; e < 8; ++e) acc[e] += ed * vals[d][e];
            }
            ushort_t pk[8];
#pragma unroll
            for (int e = 0; e < 8; ++e) pk[e] = f2bf(acc[e]);
            *(float4*)(Wall + (size_t)(blockIdx.x * WNPB + nl) * WROW + (size_t)t * 8) =
                *(float4*)pk;
        }
    }
}

// ---------------------------------------------------------------------------
// Kernel 3: NT-GEMM, double-buffered LDS (64 KB; grid forces 2 blocks/CU so
// the extra LDS is free), global_load_lds(16B) with XOR swizzle, ONE barrier
// per K-iter: barrier waits prefetch issued the previous iter (overlapped
// with that iter's MFMA compute).
//   acc[m][j] = sum_k A[m][k]*Bt[j][k]
//   MODE 0: Ct[j][m] = acc (K-major) and Cn[m][j] = acc (node-major)
//   MODE 1: Cn[m][j] = 2*acc - Zn[m][j]
// ---------------------------------------------------------------------------
template <int MODE>
__global__ __launch_bounds__(256) void gemm_nt(const ushort_t* __restrict__ A,
                                               const ushort_t* __restrict__ Bt,
                                               const ushort_t* __restrict__ Zn,
                                               ushort_t* __restrict__ Ct,
                                               ushort_t* __restrict__ Cn) {
    const int j0 = blockIdx.x * 128;
    const int m0 = blockIdx.y * 128;
    const int tid = threadIdx.x;
    const int lane = tid & 63;
    const int l16 = lane & 15;
    const int quad = lane >> 4;
    const int w = tid >> 6;      // wave 0..3
    const int wm = (w >> 1) * 64;
    const int wj = (w & 1) * 64;
    const int lr = lane >> 3;    // staging: row-in-group 0..7
    const int lc = lane & 7;     // staging: chunk 0..7
    const int swz = lc ^ lr;     // global chunk for this LDS slot

    __shared__ ushort_t As[2][128 * 64];  // 2 x 16 KB
    __shared__ ushort_t Bs[2][128 * 64];

    f32x4 acc[4][4];
#pragma unroll
    for (int mi = 0; mi < 4; ++mi)
#pragma unroll
        for (int ji = 0; ji < 4; ++ji) acc[mi][ji] = (f32x4){0.f, 0.f, 0.f, 0.f};

    // prefetch tile 0 into buffer 0
#pragma unroll
    for (int inst = 0; inst < 4; ++inst) {
        const int rbase = w * 32 + inst * 8;
        const int row = rbase + lr;
        __builtin_amdgcn_global_load_lds(
            (gptr_t)(A + (size_t)(m0 + row) * NN + swz * 8),
            (lptr_t)&As[0][rbase * 64], 16, 0, 0);
        __builtin_amdgcn_global_load_lds(
            (gptr_t)(Bt + (size_t)(j0 + row) * NN + swz * 8),
            (lptr_t)&Bs[0][rbase * 64], 16, 0, 0);
    }

    for (int it = 0; it < NN / 64; ++it) {
        const int cur = it & 1;
        __syncthreads();  // drains prefetch into buf[cur]; fences buf[1-cur] readers

        if (it + 1 < NN / 64) {
            const int k0 = (it + 1) * 64;
#pragma unroll
            for (int inst = 0; inst < 4; ++inst) {
                const int rbase = w * 32 + inst * 8;
                const int row = rbase + lr;
                __builtin_amdgcn_global_load_lds(
                    (gptr_t)(A + (size_t)(m0 + row) * NN + k0 + swz * 8),
                    (lptr_t)&As[1 - cur][rbase * 64], 16, 0, 0);
                __builtin_amdgcn_global_load_lds(
                    (gptr_t)(Bt + (size_t)(j0 + row) * NN + k0 + swz * 8),
                    (lptr_t)&Bs[1 - cur][rbase * 64], 16, 0, 0);
            }
        }

#pragma unroll
        for (int ks = 0; ks < 64; ks += 32) {
            const int qb = (ks >> 3) + quad;
            short8 av[4], bv[4];
#pragma unroll
            for (int mi = 0; mi < 4; ++mi) {
                const int rA = wm + mi * 16 + l16;
                av[mi] = *(const short8*)&As[cur][rA * 64 + ((qb ^ (rA & 7)) << 3)];
            }
#pragma unroll
            for (int ji = 0; ji < 4; ++ji) {
                const int rB = wj + ji * 16 + l16;
                bv[ji] = *(const short8*)&Bs[cur][rB * 64 + ((qb ^ (rB & 7)) << 3)];
            }
#pragma unroll
            for (int mi = 0; mi < 4; ++mi)
#pragma unroll
                for (int ji = 0; ji < 4; ++ji)
                    acc[mi][ji] = __builtin_amdgcn_mfma_f32_16x16x32_bf16(
                        av[mi], bv[ji], acc[mi][ji], 0, 0, 0);
        }
    }

    // C/D layout (16x16x32): col j = lane&15, row m = quad*4 + reg.
#pragma unroll
    for (int mi = 0; mi < 4; ++mi) {
#pragma unroll
        for (int ji = 0; ji < 4; ++ji) {
            const int j = j0 + wj + ji * 16 + l16;
            const int mb = m0 + wm + mi * 16 + quad * 4;
            if (MODE == 0) {
                ushort_t o[4];
#pragma unroll
                for (int r = 0; r < 4; ++r) o[r] = f2bf(acc[mi][ji][r]);
                *(unsigned long long*)(Ct + (size_t)j * NN + mb) = *(unsigned long long*)o;
#pragma unroll
                for (int r = 0; r < 4; ++r) Cn[(size_t)(mb + r) * JJ + j] = o[r];
            } else {
#pragma unroll
                for (int r = 0; r < 4; ++r) {
                    const float z = bf2f(Zn[(size_t)(mb + r) * JJ + j]);
                    Cn[(size_t)(mb + r) * JJ + j] = f2bf(2.0f * acc[mi][ji][r] - z);
                }
            }
        }
    }
}

// ---------------------------------------------------------------------------
// Kernel 4: MFMA epilogue. One block per node n (n = n_base + blockIdx.x).
//   Stages xg[b][ki] from node-major xN/y1N/y2N and Wt[o][ki] from Wall
//   (contiguous 24 KB row), then [64 x 192] @ [192 x 64] via 24 MFMAs/wave.
// ---------------------------------------------------------------------------
#define XLD 200  // LDS row stride (bf16): 400 B -> 2-way bank alias (free)
__global__ __launch_bounds__(256) void out_kernel(const float* __restrict__ E,
                                                  const ushort_t* __restrict__ Wall,
                                                  const float* __restrict__ bp,
                                                  const ushort_t* __restrict__ xN,
                                                  const ushort_t* __restrict__ y1N,
                                                  const ushort_t* __restrict__ y2N,
                                                  float* __restrict__ out,
                                                  int n_base) {
    const int n = n_base + blockIdx.x;
    const int tid = threadIdx.x;

    __shared__ ushort_t xg[BB * XLD];  // 25.6 KB: xg[b][k*64+i]
    __shared__ ushort_t Wt[CC * XLD];  // 25.6 KB: Wt[o][k*64+i]
    __shared__ float bias_s[CC];

    if (tid < CC) {
        float bsum = 0.0f;
#pragma unroll
        for (int d = 0; d < ED; ++d) bsum += E[(size_t)n * ED + d] * bp[d * CC + tid];
        bias_s[tid] = bsum;
    }

    // stage X rows: 3 sources x 512 chunks of 8 bf16 (contiguous 8 KB each)
#pragma unroll
    for (int k = 0; k < KK; ++k) {
        const ushort_t* src = (k == 0) ? xN : (k == 1) ? y1N : y2N;
        const float4* srow = (const float4*)(src + (size_t)n * JJ);
        for (int idx = tid; idx < JJ / 8; idx += 256) {
            *(float4*)&xg[(idx >> 3) * XLD + k * 64 + ((idx & 7) << 3)] = srow[idx];
        }
    }
    // stage Wt from Wall row (chunk t = k*512 + o*8 + ic)
    {
        const float4* wrow = (const float4*)(Wall + (size_t)blockIdx.x * WROW);
        for (int t = tid; t < WROW / 8; t += 256) {
            const int k = t >> 9;
            const int o = (t & 511) >> 3;
            const int ic = (t & 7) << 3;
            *(float4*)&Wt[o * XLD + k * 64 + ic] = wrow[t];
        }
    }
    __syncthreads();

    const int lane = tid & 63;
    const int l16 = lane & 15;
    const int quad = lane >> 4;
    const int bm = (tid >> 6) * 16;  // wave's 16 b-rows

    f32x4 acc[4];
#pragma unroll
    for (int ji = 0; ji < 4; ++ji) acc[ji] = (f32x4){0.f, 0.f, 0.f, 0.f};

#pragma unroll
    for (int kc = 0; kc < 6; ++kc) {  // K = 192 = 6 x 32
        const short8 av = *(const short8*)&xg[(bm + l16) * XLD + kc * 32 + quad * 8];
#pragma unroll
        for (int ji = 0; ji < 4; ++ji) {
            const short8 bv = *(const short8*)&Wt[(ji * 16 + l16) * XLD + kc * 32 + quad * 8];
            acc[ji] = __builtin_amdgcn_mfma_f32_16x16x32_bf16(av, bv, acc[ji], 0, 0, 0);
        }
    }

    // C/D: col o = l16 + 16*ji, row b = bm + quad*4 + r.
#pragma unroll
    for (int ji = 0; ji < 4; ++ji) {
        const int o = ji * 16 + l16;
        const float bo = bias_s[o];
#pragma unroll
        for (int r = 0; r < 4; ++r) {
            const int b = bm + quad * 4 + r;
            out[((size_t)b * NN + n) * CC + o] = acc[ji][r] + bo;
        }
    }
}
#undef XLD

// ---------------------------------------------------------------------------
// Host launch. Workspace map (bf16 elems; MB offsets):
//   WpT@0 (0.24) | xN@0.25 (16) | y1N@16.25 (16) | y2N@32.25 (16)
//   | Ab@48.25 (8) | xT@56.25 (16) | y1T@72.25 (16)  -> 88.25 MB total.
// After gemm2, [Ab..y1T) (40 MB) is dead; Wall half (25.2 MB) aliases there.
// wall/out run per half (serial stream -> no hazard between halves).
// ---------------------------------------------------------------------------
extern "C" void kernel_launch(void* const* d_in, const int* in_sizes, int n_in,
                              void* d_out, int out_size, void* d_ws, size_t ws_size,
                              hipStream_t stream) {
    const float* x  = (const float*)d_in[0];
    const float* E  = (const float*)d_in[1];
    const float* Wp = (const float*)d_in[2];
    const float* bp = (const float*)d_in[3];

    const size_t MB = 1024 * 1024 / 2;  // elems (ushort) per MB... careful: use bytes/2
    ushort_t* base = (ushort_t*)d_ws;
    ushort_t* WpT  = base;                               // 0.25 MB region
    ushort_t* xN   = base + (size_t)(256 * 1024) / 2 * 2;        // @0.25 MB (131072 elems)
    // compute offsets in elements explicitly:
    // WpT: 30*64*64 = 122880 elems (0.234 MB) -> round region to 131072 elems (0.25 MB)
    xN  = base + 131072;                                 // [2048][4096]
    ushort_t* y1N = xN + (size_t)NN * JJ;                // [2048][4096]
    ushort_t* y2N = y1N + (size_t)NN * JJ;               // [2048][4096]
    ushort_t* Ab  = y2N + (size_t)NN * JJ;               // [2048][2048]
    ushort_t* xT  = Ab + (size_t)NN * NN;                // [4096][2048]
    ushort_t* y1T = xT + (size_t)JJ * NN;                // [4096][2048]
    ushort_t* Wall = Ab;                                 // alias over dead Ab/xT/y1T (40 MB >= 25.2)
    float* out = (float*)d_out;
    (void)MB;

    supports_kernel<<<NN, 256, 0, stream>>>(E, Ab);
    transpose_kernel<<<dim3(NN / 64, BB), 256, 0, stream>>>(x, xT, xN);
    wprep_kernel<<<ED * KK, 256, 0, stream>>>(Wp, WpT);
    // y1 = A @ x : dual output (K-major + node-major)
    gemm_nt<0><<<dim3(JJ / 128, NN / 128), 256, 0, stream>>>(Ab, xT, nullptr, y1T, y1N);
    // y2 = 2 A @ y1 - x : node-major only
    gemm_nt<1><<<dim3(JJ / 128, NN / 128), 256, 0, stream>>>(Ab, y1T, xN, nullptr, y2N);
    // halves: Wall aliases dead Ab/xT/y1T region
    const int NH = NN / 2;  // 1024 nodes per half
    wall_kernel<<<NH / WNPB, 256, 0, stream>>>(E, WpT, Wall, 0);
    out_kernel<<<NH, 256, 0, stream>>>(E, Wall, bp, xN, y1N, y2N, out, 0);
    wall_kernel<<<NH / WNPB, 256, 0, stream>>>(E, WpT, Wall, NH);
    out_kernel<<<NH, 256, 0, stream>>>(E, Wall, bp, xN, y1N, y2N, out, NH);
}

// Round 6
// 218.064 us; speedup vs baseline: 1.1606x; 1.1606x over previous
//
#include <hip/hip_runtime.h>

// B=64, N=2048, DIM_IN=DIM_OUT=64, CHEB_K=3, EMBED_DIM=10
#define NN 2048
#define BB 64
#define CC 64
#define ED 10
#define KK 3
#define JJ (BB * CC)   // 4096

typedef unsigned short ushort_t;
typedef __attribute__((ext_vector_type(8))) short short8;   // 8 bf16 = 4 VGPRs
typedef __attribute__((ext_vector_type(4))) float f32x4;

typedef const __attribute__((address_space(1))) unsigned* gptr_t;
typedef __attribute__((address_space(3))) unsigned* lptr_t;

static __device__ __forceinline__ ushort_t f2bf(float f) {
    union { float f; unsigned u; } x{f};
    unsigned r = x.u + 0x7FFF + ((x.u >> 16) & 1);  // RTN-even
    return (ushort_t)(r >> 16);
}
static __device__ __forceinline__ float bf2f(ushort_t h) {
    union { unsigned u; float f; } x;
    x.u = ((unsigned)h) << 16;
    return x.f;
}

// ---------------------------------------------------------------------------
// Kernel 1 (merged prep): blockIdx selects role.
//   [0, NN)            : supports — A_bf16[n][m] = softmax(relu(E E^T)) row n
//   [NN, 2*NN)         : transpose — x[b][n][c] -> xT[(b*64+c)][n], xN[n][j]
//   [2*NN, 2*NN+30)    : wprep — Wp[d][k][i][o] fp32 -> WpT[(d*3+k)][o][i] bf16
// Merging removes 2 inter-dispatch barriers; latency-bound supports blocks
// co-schedule with BW-bound transpose blocks.
// ---------------------------------------------------------------------------
__global__ __launch_bounds__(256) void prep_kernel(const float* __restrict__ E,
                                                   const float* __restrict__ x,
                                                   const float* __restrict__ Wp,
                                                   ushort_t* __restrict__ Ab,
                                                   ushort_t* __restrict__ xT,
                                                   ushort_t* __restrict__ xN,
                                                   ushort_t* __restrict__ WpT) {
    const int bid = blockIdx.x;
    const int tid = threadIdx.x;

    __shared__ float tb[64][68];
    __shared__ float red[8];

    if (bid < NN) {
        // ---- supports row n = bid ----
        const int n = bid;
        float en[ED];
#pragma unroll
        for (int d = 0; d < ED; ++d) en[d] = E[n * ED + d];

        float sv[NN / 256];
        float lmax = 0.0f;  // relu >= 0
#pragma unroll
        for (int j = 0; j < NN / 256; ++j) {
            const int m = tid + j * 256;
            const float* Em = E + m * ED;
            float dot = 0.0f;
#pragma unroll
            for (int d = 0; d < ED; ++d) dot += en[d] * Em[d];
            float s = fmaxf(dot, 0.0f);
            sv[j] = s;
            lmax = fmaxf(lmax, s);
        }
#pragma unroll
        for (int off = 32; off > 0; off >>= 1) lmax = fmaxf(lmax, __shfl_down(lmax, off, 64));
        if ((tid & 63) == 0) red[tid >> 6] = lmax;
        __syncthreads();
        const float bmax = fmaxf(fmaxf(red[0], red[1]), fmaxf(red[2], red[3]));

        float lsum = 0.0f;
#pragma unroll
        for (int j = 0; j < NN / 256; ++j) {
            sv[j] = __expf(sv[j] - bmax);
            lsum += sv[j];
        }
#pragma unroll
        for (int off = 32; off > 0; off >>= 1) lsum += __shfl_down(lsum, off, 64);
        if ((tid & 63) == 0) red[4 + (tid >> 6)] = lsum;
        __syncthreads();
        const float inv = 1.0f / (red[4] + red[5] + red[6] + red[7]);

#pragma unroll
        for (int j = 0; j < NN / 256; ++j) {
            Ab[(size_t)n * NN + tid + j * 256] = f2bf(sv[j] * inv);
        }
    } else if (bid < 2 * NN) {
        // ---- transpose tile ----
        const int t = bid - NN;
        const int n0 = (t & 31) * 64;
        const int b = t >> 5;

#pragma unroll
        for (int l = 0; l < 4; ++l) {
            const int idx = tid + l * 256;
            const int nn = idx >> 4;
            const int c4 = (idx & 15) << 2;
            const float4 v = *(const float4*)(x + ((size_t)b * NN + n0 + nn) * CC + c4);
            tb[c4 + 0][nn] = v.x;
            tb[c4 + 1][nn] = v.y;
            tb[c4 + 2][nn] = v.z;
            tb[c4 + 3][nn] = v.w;
        }
        __syncthreads();

#pragma unroll
        for (int l = 0; l < 2; ++l) {
            const int idx = tid + l * 256;
            const int c = idx >> 3;
            const int ch = (idx & 7) << 3;
            ushort_t pack[8];
#pragma unroll
            for (int e = 0; e < 8; ++e) pack[e] = f2bf(tb[c][ch + e]);
            *(float4*)(xT + (size_t)(b * 64 + c) * NN + n0 + ch) = *(float4*)pack;
        }
#pragma unroll
        for (int l = 0; l < 2; ++l) {
            const int idx = tid + l * 256;
            const int nn = idx >> 3;
            const int cg = (idx & 7) << 3;
            ushort_t pack[8];
#pragma unroll
            for (int e = 0; e < 8; ++e) pack[e] = f2bf(tb[cg + e][nn]);
            *(float4*)(xN + (size_t)(n0 + nn) * JJ + b * 64 + cg) = *(float4*)pack;
        }
    } else {
        // ---- wprep slice dk = bid - 2*NN ----
        const int dk = bid - 2 * NN;
        const float* src = Wp + (size_t)dk * CC * CC;

#pragma unroll
        for (int l = 0; l < 4; ++l) {
            const int idx = tid + l * 256;
            const int i = idx >> 4;
            const int o4 = (idx & 15) << 2;
            const float4 v = *(const float4*)(src + i * CC + o4);
            tb[o4 + 0][i] = v.x;
            tb[o4 + 1][i] = v.y;
            tb[o4 + 2][i] = v.z;
            tb[o4 + 3][i] = v.w;
        }
        __syncthreads();

#pragma unroll
        for (int l = 0; l < 2; ++l) {
            const int idx = tid + l * 256;
            const int o = idx >> 3;
            const int ic = (idx & 7) << 3;
            ushort_t pack[8];
#pragma unroll
            for (int e = 0; e < 8; ++e) pack[e] = f2bf(tb[o][ic + e]);
            *(float4*)(WpT + (size_t)dk * CC * CC + o * CC + ic) = *(float4*)pack;
        }
    }
}

// ---------------------------------------------------------------------------
// Kernel 2: NT-GEMM, double-buffered LDS (64 KB; grid forces 2 blocks/CU so
// the extra LDS is free), global_load_lds(16B) with XOR swizzle, ONE barrier
// per K-iter (prefetch issued previous iter overlaps that iter's MFMAs).
//   acc[m][j] = sum_k A[m][k]*Bt[j][k]
//   MODE 0: Ct[j][m] = acc (K-major) and Cn[m][j] = acc (node-major)
//   MODE 1: Cn[m][j] = 2*acc - Zn[m][j]
// ---------------------------------------------------------------------------
template <int MODE>
__global__ __launch_bounds__(256) void gemm_nt(const ushort_t* __restrict__ A,
                                               const ushort_t* __restrict__ Bt,
                                               const ushort_t* __restrict__ Zn,
                                               ushort_t* __restrict__ Ct,
                                               ushort_t* __restrict__ Cn) {
    const int j0 = blockIdx.x * 128;
    const int m0 = blockIdx.y * 128;
    const int tid = threadIdx.x;
    const int lane = tid & 63;
    const int l16 = lane & 15;
    const int quad = lane >> 4;
    const int w = tid >> 6;      // wave 0..3
    const int wm = (w >> 1) * 64;
    const int wj = (w & 1) * 64;
    const int lr = lane >> 3;    // staging: row-in-group 0..7
    const int lc = lane & 7;     // staging: chunk 0..7
    const int swz = lc ^ lr;     // global chunk for this LDS slot

    __shared__ ushort_t As[2][128 * 64];  // 2 x 16 KB
    __shared__ ushort_t Bs[2][128 * 64];

    f32x4 acc[4][4];
#pragma unroll
    for (int mi = 0; mi < 4; ++mi)
#pragma unroll
        for (int ji = 0; ji < 4; ++ji) acc[mi][ji] = (f32x4){0.f, 0.f, 0.f, 0.f};

    // prefetch tile 0 into buffer 0
#pragma unroll
    for (int inst = 0; inst < 4; ++inst) {
        const int rbase = w * 32 + inst * 8;
        const int row = rbase + lr;
        __builtin_amdgcn_global_load_lds(
            (gptr_t)(A + (size_t)(m0 + row) * NN + swz * 8),
            (lptr_t)&As[0][rbase * 64], 16, 0, 0);
        __builtin_amdgcn_global_load_lds(
            (gptr_t)(Bt + (size_t)(j0 + row) * NN + swz * 8),
            (lptr_t)&Bs[0][rbase * 64], 16, 0, 0);
    }

    for (int it = 0; it < NN / 64; ++it) {
        const int cur = it & 1;
        __syncthreads();  // drains prefetch into buf[cur]; fences buf[1-cur] readers

        if (it + 1 < NN / 64) {
            const int k0 = (it + 1) * 64;
#pragma unroll
            for (int inst = 0; inst < 4; ++inst) {
                const int rbase = w * 32 + inst * 8;
                const int row = rbase + lr;
                __builtin_amdgcn_global_load_lds(
                    (gptr_t)(A + (size_t)(m0 + row) * NN + k0 + swz * 8),
                    (lptr_t)&As[1 - cur][rbase * 64], 16, 0, 0);
                __builtin_amdgcn_global_load_lds(
                    (gptr_t)(Bt + (size_t)(j0 + row) * NN + k0 + swz * 8),
                    (lptr_t)&Bs[1 - cur][rbase * 64], 16, 0, 0);
            }
        }

#pragma unroll
        for (int ks = 0; ks < 64; ks += 32) {
            const int qb = (ks >> 3) + quad;
            short8 av[4], bv[4];
#pragma unroll
            for (int mi = 0; mi < 4; ++mi) {
                const int rA = wm + mi * 16 + l16;
                av[mi] = *(const short8*)&As[cur][rA * 64 + ((qb ^ (rA & 7)) << 3)];
            }
#pragma unroll
            for (int ji = 0; ji < 4; ++ji) {
                const int rB = wj + ji * 16 + l16;
                bv[ji] = *(const short8*)&Bs[cur][rB * 64 + ((qb ^ (rB & 7)) << 3)];
            }
#pragma unroll
            for (int mi = 0; mi < 4; ++mi)
#pragma unroll
                for (int ji = 0; ji < 4; ++ji)
                    acc[mi][ji] = __builtin_amdgcn_mfma_f32_16x16x32_bf16(
                        av[mi], bv[ji], acc[mi][ji], 0, 0, 0);
        }
    }

    // C/D layout (16x16x32): col j = lane&15, row m = quad*4 + reg.
#pragma unroll
    for (int mi = 0; mi < 4; ++mi) {
#pragma unroll
        for (int ji = 0; ji < 4; ++ji) {
            const int j = j0 + wj + ji * 16 + l16;
            const int mb = m0 + wm + mi * 16 + quad * 4;
            if (MODE == 0) {
                ushort_t o[4];
#pragma unroll
                for (int r = 0; r < 4; ++r) o[r] = f2bf(acc[mi][ji][r]);
                *(unsigned long long*)(Ct + (size_t)j * NN + mb) = *(unsigned long long*)o;
#pragma unroll
                for (int r = 0; r < 4; ++r) Cn[(size_t)(mb + r) * JJ + j] = o[r];
            } else {
#pragma unroll
                for (int r = 0; r < 4; ++r) {
                    const float z = bf2f(Zn[(size_t)(mb + r) * JJ + j]);
                    Cn[(size_t)(mb + r) * JJ + j] = f2bf(2.0f * acc[mi][ji][r] - z);
                }
            }
        }
    }
}

// ---------------------------------------------------------------------------
// Kernel 3: MFMA epilogue (round-4 version — its WpT re-read is L2-resident
// and near the 15 us L2 floor; the round-5 Wall precompute regressed).
// One block per node n: [B=64 x KI=192] @ [KI=192 x O=64] via 24 MFMAs/wave.
// ---------------------------------------------------------------------------
#define XLD 200  // LDS row stride (bf16): 400 B -> 2-way bank alias (free)
__global__ __launch_bounds__(256) void out_kernel(const float* __restrict__ E,
                                                  const ushort_t* __restrict__ WpT,
                                                  const float* __restrict__ bp,
                                                  const ushort_t* __restrict__ xN,
                                                  const ushort_t* __restrict__ y1N,
                                                  const ushort_t* __restrict__ y2N,
                                                  float* __restrict__ out) {
    const int n = blockIdx.x;
    const int tid = threadIdx.x;

    __shared__ ushort_t xg[BB * XLD];  // 25.6 KB: xg[b][k*64+i]
    __shared__ ushort_t Wt[CC * XLD];  // 25.6 KB: Wt[o][k*64+i]
    __shared__ float en_s[ED];
    __shared__ float bias_s[CC];

    if (tid < ED) en_s[tid] = E[n * ED + tid];
    __syncthreads();

    float en[ED];
#pragma unroll
    for (int d = 0; d < ED; ++d) en[d] = en_s[d];

    if (tid < CC) {
        float bsum = 0.0f;
#pragma unroll
        for (int d = 0; d < ED; ++d) bsum += en[d] * bp[d * CC + tid];
        bias_s[tid] = bsum;
    }

    // stage X rows: 3 sources x 512 chunks of 8 bf16 (contiguous 8 KB each)
#pragma unroll
    for (int k = 0; k < KK; ++k) {
        const ushort_t* src = (k == 0) ? xN : (k == 1) ? y1N : y2N;
        const float4* srow = (const float4*)(src + (size_t)n * JJ);
        for (int idx = tid; idx < JJ / 8; idx += 256) {
            *(float4*)&xg[(idx >> 3) * XLD + k * 64 + ((idx & 7) << 3)] = srow[idx];
        }
    }

    // synthesize Wt[o][ki] bf16: 1536 chunks of 8, fp32 accumulate over d
    for (int t = tid; t < CC * 24; t += 256) {
        const int o = t / 24;
        const int kc = t % 24;
        const int k = kc >> 3;
        const int ic = (kc & 7) << 3;
        float s[8];
#pragma unroll
        for (int e = 0; e < 8; ++e) s[e] = 0.0f;
#pragma unroll
        for (int d = 0; d < ED; ++d) {
            const float4 wv4 = *(const float4*)(WpT + ((size_t)(d * KK + k) * CC + o) * CC + ic);
            const ushort_t* wp = (const ushort_t*)&wv4;
#pragma unroll
            for (int e = 0; e < 8; ++e) s[e] += en[d] * bf2f(wp[e]);
        }
        ushort_t pack[8];
#pragma unroll
        for (int e = 0; e < 8; ++e) pack[e] = f2bf(s[e]);
        *(float4*)&Wt[o * XLD + k * 64 + ic] = *(float4*)pack;
    }
    __syncthreads();

    const int lane = tid & 63;
    const int l16 = lane & 15;
    const int quad = lane >> 4;
    const int bm = (tid >> 6) * 16;  // wave's 16 b-rows

    f32x4 acc[4];
#pragma unroll
    for (int ji = 0; ji < 4; ++ji) acc[ji] = (f32x4){0.f, 0.f, 0.f, 0.f};

#pragma unroll
    for (int kc = 0; kc < 6; ++kc) {  // K = 192 = 6 x 32
        const short8 av = *(const short8*)&xg[(bm + l16) * XLD + kc * 32 + quad * 8];
#pragma unroll
        for (int ji = 0; ji < 4; ++ji) {
            const short8 bv = *(const short8*)&Wt[(ji * 16 + l16) * XLD + kc * 32 + quad * 8];
            acc[ji] = __builtin_amdgcn_mfma_f32_16x16x32_bf16(av, bv, acc[ji], 0, 0, 0);
        }
    }

    // C/D: col o = l16 + 16*ji, row b = bm + quad*4 + r.
#pragma unroll
    for (int ji = 0; ji < 4; ++ji) {
        const int o = ji * 16 + l16;
        const float bo = bias_s[o];
#pragma unroll
        for (int r = 0; r < 4; ++r) {
            const int b = bm + quad * 4 + r;
            out[((size_t)b * NN + n) * CC + o] = acc[ji][r] + bo;
        }
    }
}
#undef XLD

// ---------------------------------------------------------------------------
// Host launch: 4 dispatches total.
// Workspace (bf16): Ab 8 | xT 16 | xN 16 | y1T 16 | y1N 16 | y2N 16 | WpT 0.24
//   = 88.25 MB.
// ---------------------------------------------------------------------------
extern "C" void kernel_launch(void* const* d_in, const int* in_sizes, int n_in,
                              void* d_out, int out_size, void* d_ws, size_t ws_size,
                              hipStream_t stream) {
    const float* x  = (const float*)d_in[0];
    const float* E  = (const float*)d_in[1];
    const float* Wp = (const float*)d_in[2];
    const float* bp = (const float*)d_in[3];

    ushort_t* Ab  = (ushort_t*)d_ws;                    // [2048][2048]
    ushort_t* xT  = Ab + (size_t)NN * NN;               // [4096][2048]
    ushort_t* xN  = xT + (size_t)JJ * NN;               // [2048][4096]
    ushort_t* y1T = xN + (size_t)NN * JJ;               // [4096][2048]
    ushort_t* y1N = y1T + (size_t)JJ * NN;              // [2048][4096]
    ushort_t* y2N = y1N + (size_t)NN * JJ;              // [2048][4096]
    ushort_t* WpT = y2N + (size_t)NN * JJ;              // [30][64][64]
    float* out = (float*)d_out;

    prep_kernel<<<2 * NN + ED * KK, 256, 0, stream>>>(E, x, Wp, Ab, xT, xN, WpT);
    // y1 = A @ x : dual output (K-major + node-major)
    gemm_nt<0><<<dim3(JJ / 128, NN / 128), 256, 0, stream>>>(Ab, xT, nullptr, y1T, y1N);
    // y2 = 2 A @ y1 - x : node-major only
    gemm_nt<1><<<dim3(JJ / 128, NN / 128), 256, 0, stream>>>(Ab, y1T, xN, nullptr, y2N);
    out_kernel<<<NN, 256, 0, stream>>>(E, WpT, bp, xN, y1N, y2N, out);
}